// Round 1
// 253.310 us; speedup vs baseline: 1.0412x; 1.0412x over previous
//
#include <hip/hip_runtime.h>

#define B_    8
#define N_    2048
#define H_    512
#define K_    64
#define NROWS 16384            // B_*N_
#define SEGS  8                // m-split factor in dist

typedef __attribute__((ext_vector_type(8))) __bf16 bf16x8;
typedef __attribute__((ext_vector_type(4))) float  floatx4;

#define MFMA(a, b, c) __builtin_amdgcn_mfma_f32_16x16x32_bf16((a), (b), (c), 0, 0, 0)

// ---------------------------------------------------------------------------
// Kernel 0: W -> bf16 hi/lo.  Whilo layout: [sel(q=0,k=1)][hi=0,lo=1][64][512]
// ---------------------------------------------------------------------------
__global__ __launch_bounds__(256) void wcvt_kernel(
    const float* __restrict__ Wq, const float* __restrict__ Wk,
    __bf16* __restrict__ Whilo)
{
    const int i = blockIdx.x * 256 + threadIdx.x;     // 0..65535
    const bool isQ = i < 32768;
    const int off = isQ ? i : i - 32768;
    const float f = isQ ? Wq[off] : Wk[off];
    const __bf16 h = (__bf16)f;
    const __bf16 l = (__bf16)(f - (float)h);
    const int base = isQ ? 0 : 65536;
    Whilo[base + off] = h;
    Whilo[base + 32768 + off] = l;
}

// ---------------------------------------------------------------------------
// Kernel 1: projections via MFMA (hi/lo 3-pass), no LDS.
// v2: 256 threads = 4 waves/block, 16 rows per wave -> 2048 waves (2/SIMD,
// was 1/SIMD).  Explicit next-iteration A-tile prefetch hides HBM latency
// under the convert+MFMA body.
// Grid 512 blocks over 32768 rows (first 16384 -> q from x, rest -> k from y).
// ---------------------------------------------------------------------------
__global__ __launch_bounds__(256) void proj_kernel(
    const float* __restrict__ x, const float* __restrict__ y,
    const __bf16* __restrict__ Whilo,
    const float* __restrict__ bq, const float* __restrict__ bk,
    __bf16* __restrict__ qh, __bf16* __restrict__ ql,
    float* __restrict__ sq)
{
    const int tid  = threadIdx.x;
    const int wv   = tid >> 6;                        // 0..3
    const int lane = tid & 63;
    const int quad = lane >> 4;
    const int l16  = lane & 15;
    const int rowbase = blockIdx.x * 64 + wv * 16;    // global row in [0,32768)
    const bool isQ = rowbase < NROWS;
    const float* __restrict__ X   = isQ ? x : y;
    const int xrow = (isQ ? rowbase : rowbase - NROWS) + l16;
    const __bf16* __restrict__ Whi = Whilo + (isQ ? 0 : 2 * 32768);
    const __bf16* __restrict__ Wlo = Whi + 32768;
    const float* __restrict__ bias = isQ ? bq : bk;
    const float* __restrict__ Xr = X + (size_t)xrow * H_;

    floatx4 acc[4];
    #pragma unroll
    for (int ot = 0; ot < 4; ++ot)
        acc[ot] = floatx4{0.f, 0.f, 0.f, 0.f};

    // prefetch first A tile
    float4 f0 = *reinterpret_cast<const float4*>(&Xr[quad * 8]);
    float4 f1 = *reinterpret_cast<const float4*>(&Xr[quad * 8 + 4]);

    for (int it = 0; it < 16; ++it) {
        // issue next iteration's A loads before the compute body
        const int nk0 = (it < 15 ? it + 1 : it) * 32 + quad * 8;
        const float4 nf0 = *reinterpret_cast<const float4*>(&Xr[nk0]);
        const float4 nf1 = *reinterpret_cast<const float4*>(&Xr[nk0 + 4]);

        const float fv[8] = {f0.x, f0.y, f0.z, f0.w, f1.x, f1.y, f1.z, f1.w};
        bf16x8 ahi, alo;
        #pragma unroll
        for (int j = 0; j < 8; ++j) {
            const __bf16 h = (__bf16)fv[j];
            ahi[j] = h;
            alo[j] = (__bf16)(fv[j] - (float)h);
        }

        const int k0 = it * 32 + quad * 8;
        #pragma unroll
        for (int ot = 0; ot < 4; ++ot) {
            const int wrow = ot * 16 + l16;
            const bf16x8 bhi = *reinterpret_cast<const bf16x8*>(&Whi[(size_t)wrow * H_ + k0]);
            const bf16x8 blo = *reinterpret_cast<const bf16x8*>(&Wlo[(size_t)wrow * H_ + k0]);
            acc[ot] = MFMA(ahi, bhi, acc[ot]);
            acc[ot] = MFMA(ahi, blo, acc[ot]);
            acc[ot] = MFMA(alo, bhi, acc[ot]);
        }
        f0 = nf0; f1 = nf1;
    }

    // epilogue: + bias, emit bf16 hi/lo and row sums of squares
    float bv[4];
    #pragma unroll
    for (int ot = 0; ot < 4; ++ot) bv[ot] = bias[ot * 16 + l16];

    float ss[4] = {0.f, 0.f, 0.f, 0.f};
    #pragma unroll
    for (int ot = 0; ot < 4; ++ot)
        #pragma unroll
        for (int r = 0; r < 4; ++r) {
            const float qv = acc[ot][r] + bv[ot];
            acc[ot][r] = qv;
            ss[r] = fmaf(qv, qv, ss[r]);
        }
    #pragma unroll
    for (int off = 1; off < 16; off <<= 1)
        #pragma unroll
        for (int r = 0; r < 4; ++r)
            ss[r] += __shfl_xor(ss[r], off);

    const int row0 = rowbase + quad * 4;              // + r
    if (l16 == 0) {
        #pragma unroll
        for (int r = 0; r < 4; ++r) sq[row0 + r] = ss[r];
    }
    #pragma unroll
    for (int ot = 0; ot < 4; ++ot)
        #pragma unroll
        for (int r = 0; r < 4; ++r) {
            const size_t idx = (size_t)(row0 + r) * K_ + ot * 16 + l16;
            const float qv = acc[ot][r];
            const __bf16 h = (__bf16)qv;
            qh[idx] = h;
            ql[idx] = (__bf16)(qv - (float)h);
        }
}

// ---------------------------------------------------------------------------
// Kernel 2 (v2): partial mins with 8-way m-split.
// Wave = 32 n-rows (2 row-tiles) x one 256-m segment (16 subtiles).
// 4096 waves (4/SIMD, was 1/SIMD); two independent MFMA chains per subtile.
// Emits pmin[n][seg] = min over segment of (kk[m] - 2*q.k); qq added in
// combine. Min order change is exact (associative), numerics unchanged.
// ---------------------------------------------------------------------------
__global__ __launch_bounds__(256, 4) void dist_kernel(
    const __bf16* __restrict__ qh, const __bf16* __restrict__ ql,
    const float* __restrict__ sq, float* __restrict__ pmin)
{
    const int tid  = threadIdx.x;
    const int wv   = tid >> 6;
    const int lane = tid & 63;
    const int quad = lane >> 4;
    const int l16  = lane & 15;
    const int wid  = blockIdx.x * 4 + wv;   // 0..4095
    const int rg   = wid & 511;             // row-group of 32 rows
    const int seg  = wid >> 9;              // 0..7 (m segment)
    const int b    = rg >> 6;               // 64 groups per batch
    const int nrow = (rg & 63) * 32;        // within batch
    const size_t qbase = (size_t)(b * N_ + nrow);

    bf16x8 ahi[2][2], alo[2][2];
    #pragma unroll
    for (int rt = 0; rt < 2; ++rt) {
        const size_t qrow = qbase + rt * 16 + l16;
        ahi[rt][0] = *reinterpret_cast<const bf16x8*>(&qh[qrow * K_ + quad * 8]);
        ahi[rt][1] = *reinterpret_cast<const bf16x8*>(&qh[qrow * K_ + 32 + quad * 8]);
        alo[rt][0] = *reinterpret_cast<const bf16x8*>(&ql[qrow * K_ + quad * 8]);
        alo[rt][1] = *reinterpret_cast<const bf16x8*>(&ql[qrow * K_ + 32 + quad * 8]);
    }

    const __bf16* __restrict__ kh = qh + (size_t)NROWS * K_;
    const __bf16* __restrict__ kl = ql + (size_t)NROWS * K_;
    const float*  __restrict__ kk = sq + NROWS;

    floatx4 runmin[2];
    runmin[0] = floatx4{1e30f, 1e30f, 1e30f, 1e30f};
    runmin[1] = floatx4{1e30f, 1e30f, 1e30f, 1e30f};

    const int msEnd = seg * 16 + 16;
    #pragma unroll 2
    for (int ms = seg * 16; ms < msEnd; ++ms) {
        const size_t krow = (size_t)(b * N_ + ms * 16 + l16);
        const bf16x8 bh0 = *reinterpret_cast<const bf16x8*>(&kh[krow * K_ + quad * 8]);
        const bf16x8 bh1 = *reinterpret_cast<const bf16x8*>(&kh[krow * K_ + 32 + quad * 8]);
        const bf16x8 bl0 = *reinterpret_cast<const bf16x8*>(&kl[krow * K_ + quad * 8]);
        const bf16x8 bl1 = *reinterpret_cast<const bf16x8*>(&kl[krow * K_ + 32 + quad * 8]);
        const float kkv = kk[b * N_ + ms * 16 + l16];

        floatx4 a0 = floatx4{0.f, 0.f, 0.f, 0.f};
        floatx4 a1 = floatx4{0.f, 0.f, 0.f, 0.f};
        a0 = MFMA(ahi[0][0], bh0, a0);
        a1 = MFMA(ahi[1][0], bh0, a1);
        a0 = MFMA(ahi[0][1], bh1, a0);
        a1 = MFMA(ahi[1][1], bh1, a1);
        a0 = MFMA(ahi[0][0], bl0, a0);
        a1 = MFMA(ahi[1][0], bl0, a1);
        a0 = MFMA(ahi[0][1], bl1, a0);
        a1 = MFMA(ahi[1][1], bl1, a1);
        a0 = MFMA(alo[0][0], bh0, a0);
        a1 = MFMA(alo[1][0], bh0, a1);
        a0 = MFMA(alo[0][1], bh1, a0);
        a1 = MFMA(alo[1][1], bh1, a1);

        #pragma unroll
        for (int r = 0; r < 4; ++r) {
            runmin[0][r] = fminf(runmin[0][r], fmaf(-2.f, a0[r], kkv));
            runmin[1][r] = fminf(runmin[1][r], fmaf(-2.f, a1[r], kkv));
        }
    }

    #pragma unroll
    for (int off = 1; off < 16; off <<= 1)
        #pragma unroll
        for (int rt = 0; rt < 2; ++rt)
            #pragma unroll
            for (int r = 0; r < 4; ++r)
                runmin[rt][r] = fminf(runmin[rt][r], __shfl_xor(runmin[rt][r], off));

    if (l16 == 0) {
        #pragma unroll
        for (int rt = 0; rt < 2; ++rt)
            #pragma unroll
            for (int r = 0; r < 4; ++r) {
                const int row = nrow + rt * 16 + quad * 4 + r;
                pmin[(size_t)(b * N_ + row) * SEGS + seg] = runmin[rt][r];
            }
    }
}

// ---------------------------------------------------------------------------
// Kernel 2b: combine the 8 partial mins, add qq, exponentiate.
// ---------------------------------------------------------------------------
__global__ __launch_bounds__(256) void combine_kernel(
    const float* __restrict__ pmin, const float* __restrict__ sq,
    float* __restrict__ w)
{
    const int i = blockIdx.x * 256 + threadIdx.x;     // 0..16383
    const float4 a = reinterpret_cast<const float4*>(pmin)[i * 2];
    const float4 c = reinterpret_cast<const float4*>(pmin)[i * 2 + 1];
    const float m = fminf(fminf(fminf(a.x, a.y), fminf(a.z, a.w)),
                          fminf(fminf(c.x, c.y), fminf(c.z, c.w)));
    w[i] = expf(-(m + sq[i]));
}

// ---------------------------------------------------------------------------
// Kernel 3: out[b,n,m] = w[b,n] * w[b,m]  (134 MB, write-bound, float4 stores)
// ---------------------------------------------------------------------------
__global__ __launch_bounds__(256) void outer_kernel(
    const float* __restrict__ w, float4* __restrict__ out)
{
    const int f = blockIdx.x * 256 + threadIdx.x;  // float4 index, 2^23 total
    const int m4 = f & 511;
    const int n  = (f >> 9) & 2047;
    const int b  = f >> 20;
    const float wn = w[(b << 11) + n];
    const float4 wm = reinterpret_cast<const float4*>(w)[(b << 9) + m4];
    float4 o;
    o.x = wn * wm.x; o.y = wn * wm.y; o.z = wn * wm.z; o.w = wn * wm.w;
    out[f] = o;
}

// ---------------------------------------------------------------------------
extern "C" void kernel_launch(void* const* d_in, const int* in_sizes, int n_in,
                              void* d_out, int out_size, void* d_ws, size_t ws_size,
                              hipStream_t stream)
{
    const float* x  = (const float*)d_in[0];
    const float* y  = (const float*)d_in[1];
    const float* Wq = (const float*)d_in[2];
    const float* bq = (const float*)d_in[3];
    const float* Wk = (const float*)d_in[4];
    const float* bk = (const float*)d_in[5];
    float* out = (float*)d_out;

    char* ws = (char*)d_ws;
    __bf16* qh    = (__bf16*)ws;                          // RTOT*K_ = 2M elems, 4 MB
    __bf16* ql    = (__bf16*)(ws + 4194304);              // 4 MB
    float*  sq    = (float*)(ws + 8388608);               // 32768 floats, 128 KB
    __bf16* Whilo = (__bf16*)(ws + 8519680);              // 4*32768 elems, 256 KB
    float*  w     = (float*)(ws + 8781824);               // 16384 floats, 64 KB
    float*  pmin  = (float*)(ws + 8847360);               // 16384*8 floats, 512 KB

    wcvt_kernel<<<256, 256, 0, stream>>>(Wq, Wk, Whilo);
    proj_kernel<<<512, 256, 0, stream>>>(x, y, Whilo, bq, bk, qh, ql, sq);
    dist_kernel<<<1024, 256, 0, stream>>>(qh, ql, sq, pmin);
    combine_kernel<<<64, 256, 0, stream>>>(pmin, sq, w);
    outer_kernel<<<32768, 256, 0, stream>>>(w, (float4*)out);
}

// Round 2
// 247.247 us; speedup vs baseline: 1.0668x; 1.0245x over previous
//
#include <hip/hip_runtime.h>

#define B_    8
#define N_    2048
#define H_    512
#define K_    64
#define NROWS 16384            // B_*N_
#define SEGS  8                // m-split factor in dist

typedef __attribute__((ext_vector_type(8))) __bf16 bf16x8;
typedef __attribute__((ext_vector_type(4))) float  floatx4;

#define MFMA(a, b, c) __builtin_amdgcn_mfma_f32_16x16x32_bf16((a), (b), (c), 0, 0, 0)

// ---------------------------------------------------------------------------
// Kernel 0: W -> bf16 hi/lo.  Whilo layout: [sel(q=0,k=1)][hi=0,lo=1][64][512]
// ---------------------------------------------------------------------------
__global__ __launch_bounds__(256) void wcvt_kernel(
    const float* __restrict__ Wq, const float* __restrict__ Wk,
    __bf16* __restrict__ Whilo)
{
    const int i = blockIdx.x * 256 + threadIdx.x;     // 0..65535
    const bool isQ = i < 32768;
    const int off = isQ ? i : i - 32768;
    const float f = isQ ? Wq[off] : Wk[off];
    const __bf16 h = (__bf16)f;
    const __bf16 l = (__bf16)(f - (float)h);
    const int base = isQ ? 0 : 65536;
    Whilo[base + off] = h;
    Whilo[base + 32768 + off] = l;
}

// ---------------------------------------------------------------------------
// Kernel 1: projections via MFMA (hi/lo 3-pass), no LDS.
// v3: depth-2 A-tile prefetch (two 32B/lane HBM loads in flight per wave)
// -> ~8 KB in flight per SIMD at 2 waves/SIMD, enough to saturate HBM at
// ~900 cyc latency (Little's law needs ~5.5 KB).  Arithmetic unchanged.
// ---------------------------------------------------------------------------
__global__ __launch_bounds__(256, 2) void proj_kernel(
    const float* __restrict__ x, const float* __restrict__ y,
    const __bf16* __restrict__ Whilo,
    const float* __restrict__ bq, const float* __restrict__ bk,
    __bf16* __restrict__ qh, __bf16* __restrict__ ql,
    float* __restrict__ sq)
{
    const int tid  = threadIdx.x;
    const int wv   = tid >> 6;                        // 0..3
    const int lane = tid & 63;
    const int quad = lane >> 4;
    const int l16  = lane & 15;
    const int rowbase = blockIdx.x * 64 + wv * 16;    // global row in [0,32768)
    const bool isQ = rowbase < NROWS;
    const float* __restrict__ X   = isQ ? x : y;
    const int xrow = (isQ ? rowbase : rowbase - NROWS) + l16;
    const __bf16* __restrict__ Whi = Whilo + (isQ ? 0 : 2 * 32768);
    const __bf16* __restrict__ Wlo = Whi + 32768;
    const float* __restrict__ bias = isQ ? bq : bk;
    const float* __restrict__ Xr = X + (size_t)xrow * H_;

    floatx4 acc[4];
    #pragma unroll
    for (int ot = 0; ot < 4; ++ot)
        acc[ot] = floatx4{0.f, 0.f, 0.f, 0.f};

    // depth-2 prefetch pipeline: tiles for it and it+1 in flight
    float4 f0a = *reinterpret_cast<const float4*>(&Xr[quad * 8]);
    float4 f1a = *reinterpret_cast<const float4*>(&Xr[quad * 8 + 4]);
    float4 f0b = *reinterpret_cast<const float4*>(&Xr[32 + quad * 8]);
    float4 f1b = *reinterpret_cast<const float4*>(&Xr[32 + quad * 8 + 4]);

    #pragma unroll
    for (int it = 0; it < 16; ++it) {
        // issue it+2's A loads before the compute body
        const int pit = (it < 14) ? it + 2 : 15;
        const int nk0 = pit * 32 + quad * 8;
        const float4 nf0 = *reinterpret_cast<const float4*>(&Xr[nk0]);
        const float4 nf1 = *reinterpret_cast<const float4*>(&Xr[nk0 + 4]);

        const float fv[8] = {f0a.x, f0a.y, f0a.z, f0a.w, f1a.x, f1a.y, f1a.z, f1a.w};
        bf16x8 ahi, alo;
        #pragma unroll
        for (int j = 0; j < 8; ++j) {
            const __bf16 h = (__bf16)fv[j];
            ahi[j] = h;
            alo[j] = (__bf16)(fv[j] - (float)h);
        }

        const int k0 = it * 32 + quad * 8;
        #pragma unroll
        for (int ot = 0; ot < 4; ++ot) {
            const int wrow = ot * 16 + l16;
            const bf16x8 bhi = *reinterpret_cast<const bf16x8*>(&Whi[(size_t)wrow * H_ + k0]);
            const bf16x8 blo = *reinterpret_cast<const bf16x8*>(&Wlo[(size_t)wrow * H_ + k0]);
            acc[ot] = MFMA(ahi, bhi, acc[ot]);
            acc[ot] = MFMA(ahi, blo, acc[ot]);
            acc[ot] = MFMA(alo, bhi, acc[ot]);
        }
        f0a = f0b; f1a = f1b;
        f0b = nf0; f1b = nf1;
    }

    // epilogue: + bias, emit bf16 hi/lo and row sums of squares
    float bv[4];
    #pragma unroll
    for (int ot = 0; ot < 4; ++ot) bv[ot] = bias[ot * 16 + l16];

    float ss[4] = {0.f, 0.f, 0.f, 0.f};
    #pragma unroll
    for (int ot = 0; ot < 4; ++ot)
        #pragma unroll
        for (int r = 0; r < 4; ++r) {
            const float qv = acc[ot][r] + bv[ot];
            acc[ot][r] = qv;
            ss[r] = fmaf(qv, qv, ss[r]);
        }
    #pragma unroll
    for (int off = 1; off < 16; off <<= 1)
        #pragma unroll
        for (int r = 0; r < 4; ++r)
            ss[r] += __shfl_xor(ss[r], off);

    const int row0 = rowbase + quad * 4;              // + r
    if (l16 == 0) {
        #pragma unroll
        for (int r = 0; r < 4; ++r) sq[row0 + r] = ss[r];
    }
    #pragma unroll
    for (int ot = 0; ot < 4; ++ot)
        #pragma unroll
        for (int r = 0; r < 4; ++r) {
            const size_t idx = (size_t)(row0 + r) * K_ + ot * 16 + l16;
            const float qv = acc[ot][r];
            const __bf16 h = (__bf16)qv;
            qh[idx] = h;
            ql[idx] = (__bf16)(qv - (float)h);
        }
}

// ---------------------------------------------------------------------------
// Kernel 2 (v3): partial mins, 8-way m-split, next-subtile K-frag prefetch.
// The 4 L2 loads + kk for subtile i+1 are issued before subtile i's 12-MFMA
// block, hiding ~200-cyc L2 latency under the matrix pipe.  Full unroll.
// Min order unchanged -> numerics identical.
// ---------------------------------------------------------------------------
__global__ __launch_bounds__(256, 4) void dist_kernel(
    const __bf16* __restrict__ qh, const __bf16* __restrict__ ql,
    const float* __restrict__ sq, float* __restrict__ pmin)
{
    const int tid  = threadIdx.x;
    const int wv   = tid >> 6;
    const int lane = tid & 63;
    const int quad = lane >> 4;
    const int l16  = lane & 15;
    const int wid  = blockIdx.x * 4 + wv;   // 0..4095
    const int rg   = wid & 511;             // row-group of 32 rows
    const int seg  = wid >> 9;              // 0..7 (m segment)
    const int b    = rg >> 6;               // 64 groups per batch
    const int nrow = (rg & 63) * 32;        // within batch
    const size_t qbase = (size_t)(b * N_ + nrow);

    bf16x8 ahi[2][2], alo[2][2];
    #pragma unroll
    for (int rt = 0; rt < 2; ++rt) {
        const size_t qrow = qbase + rt * 16 + l16;
        ahi[rt][0] = *reinterpret_cast<const bf16x8*>(&qh[qrow * K_ + quad * 8]);
        ahi[rt][1] = *reinterpret_cast<const bf16x8*>(&qh[qrow * K_ + 32 + quad * 8]);
        alo[rt][0] = *reinterpret_cast<const bf16x8*>(&ql[qrow * K_ + quad * 8]);
        alo[rt][1] = *reinterpret_cast<const bf16x8*>(&ql[qrow * K_ + 32 + quad * 8]);
    }

    const __bf16* __restrict__ kh = qh + (size_t)NROWS * K_;
    const __bf16* __restrict__ kl = ql + (size_t)NROWS * K_;
    const float*  __restrict__ kk = sq + NROWS;

    floatx4 runmin[2];
    runmin[0] = floatx4{1e30f, 1e30f, 1e30f, 1e30f};
    runmin[1] = floatx4{1e30f, 1e30f, 1e30f, 1e30f};

    const int ms0 = seg * 16;
    size_t krow = (size_t)(b * N_ + ms0 * 16 + l16);
    bf16x8 cbh0 = *reinterpret_cast<const bf16x8*>(&kh[krow * K_ + quad * 8]);
    bf16x8 cbh1 = *reinterpret_cast<const bf16x8*>(&kh[krow * K_ + 32 + quad * 8]);
    bf16x8 cbl0 = *reinterpret_cast<const bf16x8*>(&kl[krow * K_ + quad * 8]);
    bf16x8 cbl1 = *reinterpret_cast<const bf16x8*>(&kl[krow * K_ + 32 + quad * 8]);
    float  ckk  = kk[b * N_ + ms0 * 16 + l16];

    #pragma unroll
    for (int i = 0; i < 16; ++i) {
        // issue next subtile's loads before this subtile's MFMA block
        const int nxt = ms0 + ((i < 15) ? i + 1 : i);
        const size_t nkrow = (size_t)(b * N_ + nxt * 16 + l16);
        const bf16x8 nbh0 = *reinterpret_cast<const bf16x8*>(&kh[nkrow * K_ + quad * 8]);
        const bf16x8 nbh1 = *reinterpret_cast<const bf16x8*>(&kh[nkrow * K_ + 32 + quad * 8]);
        const bf16x8 nbl0 = *reinterpret_cast<const bf16x8*>(&kl[nkrow * K_ + quad * 8]);
        const bf16x8 nbl1 = *reinterpret_cast<const bf16x8*>(&kl[nkrow * K_ + 32 + quad * 8]);
        const float  nkk  = kk[b * N_ + nxt * 16 + l16];

        floatx4 a0 = floatx4{0.f, 0.f, 0.f, 0.f};
        floatx4 a1 = floatx4{0.f, 0.f, 0.f, 0.f};
        a0 = MFMA(ahi[0][0], cbh0, a0);
        a1 = MFMA(ahi[1][0], cbh0, a1);
        a0 = MFMA(ahi[0][1], cbh1, a0);
        a1 = MFMA(ahi[1][1], cbh1, a1);
        a0 = MFMA(ahi[0][0], cbl0, a0);
        a1 = MFMA(ahi[1][0], cbl0, a1);
        a0 = MFMA(ahi[0][1], cbl1, a0);
        a1 = MFMA(ahi[1][1], cbl1, a1);
        a0 = MFMA(alo[0][0], cbh0, a0);
        a1 = MFMA(alo[1][0], cbh0, a1);
        a0 = MFMA(alo[0][1], cbh1, a0);
        a1 = MFMA(alo[1][1], cbh1, a1);

        #pragma unroll
        for (int r = 0; r < 4; ++r) {
            runmin[0][r] = fminf(runmin[0][r], fmaf(-2.f, a0[r], ckk));
            runmin[1][r] = fminf(runmin[1][r], fmaf(-2.f, a1[r], ckk));
        }

        cbh0 = nbh0; cbh1 = nbh1; cbl0 = nbl0; cbl1 = nbl1; ckk = nkk;
    }

    #pragma unroll
    for (int off = 1; off < 16; off <<= 1)
        #pragma unroll
        for (int rt = 0; rt < 2; ++rt)
            #pragma unroll
            for (int r = 0; r < 4; ++r)
                runmin[rt][r] = fminf(runmin[rt][r], __shfl_xor(runmin[rt][r], off));

    if (l16 == 0) {
        #pragma unroll
        for (int rt = 0; rt < 2; ++rt)
            #pragma unroll
            for (int r = 0; r < 4; ++r) {
                const int row = nrow + rt * 16 + quad * 4 + r;
                pmin[(size_t)(b * N_ + row) * SEGS + seg] = runmin[rt][r];
            }
    }
}

// ---------------------------------------------------------------------------
// Kernel 2b: combine the 8 partial mins, add qq, exponentiate.
// ---------------------------------------------------------------------------
__global__ __launch_bounds__(256) void combine_kernel(
    const float* __restrict__ pmin, const float* __restrict__ sq,
    float* __restrict__ w)
{
    const int i = blockIdx.x * 256 + threadIdx.x;     // 0..16383
    const float4 a = reinterpret_cast<const float4*>(pmin)[i * 2];
    const float4 c = reinterpret_cast<const float4*>(pmin)[i * 2 + 1];
    const float m = fminf(fminf(fminf(a.x, a.y), fminf(a.z, a.w)),
                          fminf(fminf(c.x, c.y), fminf(c.z, c.w)));
    w[i] = expf(-(m + sq[i]));
}

// ---------------------------------------------------------------------------
// Kernel 3: out[b,n,m] = w[b,n] * w[b,m]  (134 MB, write-bound, float4 stores)
// ---------------------------------------------------------------------------
__global__ __launch_bounds__(256) void outer_kernel(
    const float* __restrict__ w, float4* __restrict__ out)
{
    const int f = blockIdx.x * 256 + threadIdx.x;  // float4 index, 2^23 total
    const int m4 = f & 511;
    const int n  = (f >> 9) & 2047;
    const int b  = f >> 20;
    const float wn = w[(b << 11) + n];
    const float4 wm = reinterpret_cast<const float4*>(w)[(b << 9) + m4];
    float4 o;
    o.x = wn * wm.x; o.y = wn * wm.y; o.z = wn * wm.z; o.w = wn * wm.w;
    out[f] = o;
}

// ---------------------------------------------------------------------------
extern "C" void kernel_launch(void* const* d_in, const int* in_sizes, int n_in,
                              void* d_out, int out_size, void* d_ws, size_t ws_size,
                              hipStream_t stream)
{
    const float* x  = (const float*)d_in[0];
    const float* y  = (const float*)d_in[1];
    const float* Wq = (const float*)d_in[2];
    const float* bq = (const float*)d_in[3];
    const float* Wk = (const float*)d_in[4];
    const float* bk = (const float*)d_in[5];
    float* out = (float*)d_out;

    char* ws = (char*)d_ws;
    __bf16* qh    = (__bf16*)ws;                          // RTOT*K_ = 2M elems, 4 MB
    __bf16* ql    = (__bf16*)(ws + 4194304);              // 4 MB
    float*  sq    = (float*)(ws + 8388608);               // 32768 floats, 128 KB
    __bf16* Whilo = (__bf16*)(ws + 8519680);              // 4*32768 elems, 256 KB
    float*  w     = (float*)(ws + 8781824);               // 16384 floats, 64 KB
    float*  pmin  = (float*)(ws + 8847360);               // 16384*8 floats, 512 KB

    wcvt_kernel<<<256, 256, 0, stream>>>(Wq, Wk, Whilo);
    proj_kernel<<<512, 256, 0, stream>>>(x, y, Whilo, bq, bk, qh, ql, sq);
    dist_kernel<<<1024, 256, 0, stream>>>(qh, ql, sq, pmin);
    combine_kernel<<<64, 256, 0, stream>>>(pmin, sq, w);
    outer_kernel<<<32768, 256, 0, stream>>>(w, (float4*)out);
}